// Round 1
// baseline (805.262 us; speedup 1.0000x reference)
//
#include <hip/hip_runtime.h>

#define NN 100000
#define NE 800000
#define HID 64
#define HEADS 4

__device__ __forceinline__ float wave_reduce_sum(float v) {
    #pragma unroll
    for (int o = 32; o > 0; o >>= 1) v += __shfl_down(v, o, 64);
    return v; // valid in lane 0
}

// --- tiny: c1[h] = dot(We1_h, att_e1_h), c2 = dot(We2, att_e2) ---
__global__ void k_pre(const float* __restrict__ We1, const float* __restrict__ ae1,
                      const float* __restrict__ We2, const float* __restrict__ ae2,
                      float* __restrict__ cbuf) {
    int l = threadIdx.x; // 64
    #pragma unroll
    for (int h = 0; h < HEADS; ++h) {
        float s = wave_reduce_sum(We1[h * 64 + l] * ae1[h * 64 + l]);
        if (l == 0) cbuf[h] = s;
    }
    float s2 = wave_reduce_sum(We2[l] * ae2[l]);
    if (l == 0) cbuf[4] = s2;
}

// --- per-node conv1 attention coefficients: a_src1[n,h], a_dst1[n,h] ---
__global__ void k_node1(const float* __restrict__ x, const float* __restrict__ W1,
                        const float* __restrict__ as1, const float* __restrict__ ad1,
                        float* __restrict__ a_src1, float* __restrict__ a_dst1) {
    int n = blockIdx.x;
    int t = threadIdx.x;          // 256
    int h = t >> 6, l = t & 63;
    float xv[7];
    #pragma unroll
    for (int k = 0; k < 7; ++k) xv[k] = x[n * 7 + k];
    float xh = 0.f;
    #pragma unroll
    for (int k = 0; k < 7; ++k) xh += xv[k] * W1[k * 256 + t];
    float ps = wave_reduce_sum(xh * as1[t]);
    float pd = wave_reduce_sum(xh * ad1[t]);
    if (l == 0) { a_src1[n * 4 + h] = ps; a_dst1[n * 4 + h] = pd; }
}

// --- counting sort of edges by dst: histogram ---
__global__ void k_hist(const int* __restrict__ dst, int* __restrict__ hist) {
    int e = blockIdx.x * 256 + threadIdx.x;
    if (e < NE) atomicAdd(&hist[dst[e]], 1);
}

// --- exclusive scan (single block, 1024 threads, wave-scan based) ---
__global__ void k_scan(const int* __restrict__ hist, int* __restrict__ offs) {
    __shared__ int wsum[16];
    __shared__ int carry_s;
    int t = threadIdx.x, lane = t & 63, wid = t >> 6;
    if (t == 0) carry_s = 0;
    __syncthreads();
    for (int base = 0; base < NN; base += 1024) {
        int i = base + t;
        int v = (i < NN) ? hist[i] : 0;
        int s = v;
        #pragma unroll
        for (int d = 1; d < 64; d <<= 1) { int u = __shfl_up(s, d, 64); if (lane >= d) s += u; }
        if (lane == 63) wsum[wid] = s;
        __syncthreads();
        if (wid == 0) {
            int ws_ = (lane < 16) ? wsum[lane] : 0;
            #pragma unroll
            for (int d = 1; d < 16; d <<= 1) { int u = __shfl_up(ws_, d, 64); if (lane >= d) ws_ += u; }
            if (lane < 16) wsum[lane] = ws_;
        }
        __syncthreads();
        int carry = carry_s;
        int wpre = (wid > 0) ? wsum[wid - 1] : 0;
        if (i < NN) offs[i + 1] = carry + wpre + s;
        __syncthreads();
        if (t == 1023) carry_s = carry + wsum[15];
        __syncthreads();
    }
    if (t == 0) offs[0] = 0;
}

// --- scatter edges into dst-sorted order ---
__global__ void k_scatter(const int* __restrict__ src, const int* __restrict__ dst,
                          const float* __restrict__ ea, const int* __restrict__ offs,
                          int* __restrict__ cursor, int* __restrict__ es_src,
                          float* __restrict__ es_ea) {
    int e = blockIdx.x * 256 + threadIdx.x;
    if (e >= NE) return;
    int d = dst[e];
    int pos = offs[d] + atomicAdd(&cursor[d], 1);
    es_src[pos] = src[e];
    es_ea[pos] = ea[e];
}

// --- fused: conv1 aggregate (per dst wave) -> +b1 -> ELU -> xh2 = h@W2 -> a_src2/a_dst2 ---
__global__ __launch_bounds__(512) void k_conv1(
    const float* __restrict__ x, const float* __restrict__ W1, const float* __restrict__ b1,
    const float* __restrict__ a_src1, const float* __restrict__ a_dst1,
    const float* __restrict__ cbuf, const float* __restrict__ W2,
    const float* __restrict__ as2, const float* __restrict__ ad2,
    const int* __restrict__ offs, const int* __restrict__ es_src, const float* __restrict__ es_ea,
    float* __restrict__ xh2, float* __restrict__ a_src2, float* __restrict__ a_dst2) {
    __shared__ float w2s[256 * 64];
    int t = threadIdx.x;
    for (int i = t; i < 256 * 64; i += 512) w2s[i] = W2[i];
    int lane = t & 63, wid = t >> 6;
    // W1 columns for this lane: W1[k, h*64+lane]
    float w1r[7][4];
    #pragma unroll
    for (int k = 0; k < 7; ++k)
        #pragma unroll
        for (int h = 0; h < 4; ++h) w1r[k][h] = W1[k * 256 + h * 64 + lane];
    float b1r[4];
    #pragma unroll
    for (int h = 0; h < 4; ++h) b1r[h] = b1[h * 64 + lane];
    float c1_0 = cbuf[0], c1_1 = cbuf[1], c1_2 = cbuf[2], c1_3 = cbuf[3];
    float as2l = as2[lane], ad2l = ad2[lane];
    __syncthreads();

    int step = gridDim.x * 8;
    for (int n = blockIdx.x * 8 + wid; n < NN; n += step) {
        int o0 = offs[n], o1 = offs[n + 1];
        float4 adv = *(const float4*)(a_dst1 + n * 4);
        float adh[4] = {adv.x, adv.y, adv.z, adv.w};
        float c1[4] = {c1_0, c1_1, c1_2, c1_3};
        float z[4] = {0.f, 0.f, 0.f, 0.f};
        float acc[4] = {0.f, 0.f, 0.f, 0.f};
        for (int j = o0; j < o1; ++j) {
            int s = es_src[j];
            float eav = es_ea[j];
            float4 asv = *(const float4*)(a_src1 + s * 4);
            float as_[4] = {asv.x, asv.y, asv.z, asv.w};
            float xv[7];
            #pragma unroll
            for (int k = 0; k < 7; ++k) xv[k] = x[s * 7 + k];
            #pragma unroll
            for (int h = 0; h < 4; ++h) {
                float lg = as_[h] + adh[h] + eav * c1[h];
                lg = lg >= 0.f ? lg : 0.2f * lg;
                float w = __expf(lg);
                z[h] += w;
                float xh = 0.f;
                #pragma unroll
                for (int k = 0; k < 7; ++k) xh += xv[k] * w1r[k][h];
                acc[h] += w * xh;
            }
        }
        bool has = o1 > o0;
        float hv[4];
        #pragma unroll
        for (int h = 0; h < 4; ++h) {
            float m = (has ? acc[h] / z[h] : 0.f) + b1r[h];
            hv[h] = m > 0.f ? m : (__expf(m) - 1.f);
        }
        // xh2[n, lane] = sum_k h[k] * W2[k, lane]
        float xv2 = 0.f;
        #pragma unroll
        for (int hh = 0; hh < 4; ++hh) {
            #pragma unroll 8
            for (int kl = 0; kl < 64; ++kl) {
                float hb = __shfl(hv[hh], kl, 64);
                xv2 += hb * w2s[(hh * 64 + kl) * 64 + lane];
            }
        }
        xh2[n * 64 + lane] = xv2;
        float ps = wave_reduce_sum(xv2 * as2l);
        float pd = wave_reduce_sum(xv2 * ad2l);
        if (lane == 0) { a_src2[n] = ps; a_dst2[n] = pd; }
    }
}

// --- conv2 aggregate (per dst wave) + b2, then cluster pooling partials ---
__global__ __launch_bounds__(256) void k_conv2(
    const float* __restrict__ x, const float* __restrict__ xh2,
    const float* __restrict__ a_src2, const float* __restrict__ a_dst2,
    const float* __restrict__ cbuf, const float* __restrict__ b2,
    const int* __restrict__ offs, const int* __restrict__ es_src, const float* __restrict__ es_ea,
    const int* __restrict__ assign, float* __restrict__ gacc) {
    __shared__ float csum[256];
    __shared__ float ccnt[4], ccf[4];
    int t = threadIdx.x;
    csum[t] = 0.f;
    if (t < 4) { ccnt[t] = 0.f; ccf[t] = 0.f; }
    __syncthreads();
    int lane = t & 63, wid = t >> 6;
    float c2 = cbuf[4];
    float b2l = b2[lane];
    int step = gridDim.x * 4;
    for (int n = blockIdx.x * 4 + wid; n < NN; n += step) {
        int o0 = offs[n], o1 = offs[n + 1];
        float adn = a_dst2[n];
        float z = 0.f, acc = 0.f;
        for (int j = o0; j < o1; ++j) {
            int s = es_src[j];
            float lg = a_src2[s] + adn + es_ea[j] * c2;
            lg = lg >= 0.f ? lg : 0.2f * lg;
            float w = __expf(lg);
            z += w;
            acc += w * xh2[s * 64 + lane];
        }
        float h2 = ((o1 > o0) ? acc / z : 0.f) + b2l;
        int c = assign[n];
        atomicAdd(&csum[c * 64 + lane], h2);
        if (lane == 0) {
            atomicAdd(&ccnt[c], 1.f);
            atomicAdd(&ccf[c], x[n * 7 + 6]);
        }
    }
    __syncthreads();
    atomicAdd(&gacc[t], csum[t]);
    if (t < 4) { atomicAdd(&gacc[256 + t], ccnt[t]); atomicAdd(&gacc[260 + t], ccf[t]); }
}

// --- final head: cluster means, actor MLP + softmax, critic MLP, outputs ---
__global__ void k_head(const float* __restrict__ gacc,
                       const float* __restrict__ A1, const float* __restrict__ ba1,
                       const float* __restrict__ A2, const float* __restrict__ ba2,
                       const float* __restrict__ C1, const float* __restrict__ bc1,
                       const float* __restrict__ C2, const float* __restrict__ bc2,
                       float* __restrict__ out) {
    __shared__ float zc[4][64];
    __shared__ float cfs[4];
    __shared__ float logits[4];
    int j = threadIdx.x; // 64
    #pragma unroll
    for (int c = 0; c < 4; ++c) {
        float cnt = gacc[256 + c];
        float den = fmaxf(cnt, 1.f);
        zc[c][j] = (cnt > 0.f) ? gacc[c * 64 + j] / den : 0.f;
        if (j == 0) cfs[c] = (cnt > 0.f) ? gacc[260 + c] / den : 0.f;
    }
    __syncthreads();
    // actor
    #pragma unroll
    for (int c = 0; c < 4; ++c) {
        float tv = ba1[j];
        for (int k = 0; k < 64; ++k) tv += zc[c][k] * A1[k * 64 + j];
        tv += cfs[c] * A1[64 * 64 + j];
        tv = fmaxf(tv, 0.f);
        float s = wave_reduce_sum(tv * A2[j]);
        if (j == 0) logits[c] = s + ba2[0];
    }
    // critic
    float vj = bc1[j];
    for (int k = 0; k < 256; ++k) vj += zc[k >> 6][k & 63] * C1[k * 64 + j];
    vj = fmaxf(vj, 0.f);
    float v = wave_reduce_sum(vj * C2[j]);
    __syncthreads();
    if (j == 0) {
        float m = fmaxf(fmaxf(logits[0], logits[1]), fmaxf(logits[2], logits[3]));
        float e0 = __expf(logits[0] - m), e1 = __expf(logits[1] - m);
        float e2 = __expf(logits[2] - m), e3 = __expf(logits[3] - m);
        float sum = e0 + e1 + e2 + e3;
        out[0] = e0 / sum; out[1] = e1 / sum; out[2] = e2 / sum; out[3] = e3 / sum;
        out[4] = v + bc2[0];
    }
    #pragma unroll
    for (int c = 0; c < 4; ++c) out[5 + c * 64 + j] = zc[c][j];
}

extern "C" void kernel_launch(void* const* d_in, const int* in_sizes, int n_in,
                              void* d_out, int out_size, void* d_ws, size_t ws_size,
                              hipStream_t stream) {
    const float* x    = (const float*)d_in[0];
    const int*   ei   = (const int*)d_in[1];
    const float* ea   = (const float*)d_in[2];
    const int*   asg  = (const int*)d_in[3];
    const float* W1   = (const float*)d_in[4];
    const float* as1  = (const float*)d_in[5];
    const float* ad1  = (const float*)d_in[6];
    const float* We1  = (const float*)d_in[7];
    const float* ae1  = (const float*)d_in[8];
    const float* b1   = (const float*)d_in[9];
    const float* W2   = (const float*)d_in[10];
    const float* as2  = (const float*)d_in[11];
    const float* ad2  = (const float*)d_in[12];
    const float* We2  = (const float*)d_in[13];
    const float* ae2  = (const float*)d_in[14];
    const float* b2   = (const float*)d_in[15];
    const float* A1   = (const float*)d_in[16];
    const float* ba1  = (const float*)d_in[17];
    const float* A2   = (const float*)d_in[18];
    const float* ba2  = (const float*)d_in[19];
    const float* C1   = (const float*)d_in[20];
    const float* bc1  = (const float*)d_in[21];
    const float* C2   = (const float*)d_in[22];
    const float* bc2  = (const float*)d_in[23];
    const int* src = ei;
    const int* dst = ei + NE;

    char* w = (char*)d_ws;
    size_t off = 0;
    auto alloc = [&](size_t bytes) -> void* {
        void* p = w + off;
        off += (bytes + 255) & ~(size_t)255;
        return p;
    };
    float* a_src1 = (float*)alloc(NN * 4 * sizeof(float));
    float* a_dst1 = (float*)alloc(NN * 4 * sizeof(float));
    float* a_src2 = (float*)alloc(NN * sizeof(float));
    float* a_dst2 = (float*)alloc(NN * sizeof(float));
    float* xh2    = (float*)alloc(NN * 64 * sizeof(float));
    int*   hist   = (int*)alloc(NN * sizeof(int));
    int*   offs   = (int*)alloc((NN + 1) * sizeof(int));
    int*   cursor = (int*)alloc(NN * sizeof(int));
    int*   es_src = (int*)alloc(NE * sizeof(int));
    float* es_ea  = (float*)alloc(NE * sizeof(float));
    float* cbuf   = (float*)alloc(8 * sizeof(float));
    float* gacc   = (float*)alloc(264 * sizeof(float));
    (void)ws_size; (void)n_in; (void)in_sizes; (void)out_size;

    hipMemsetAsync(hist, 0, NN * sizeof(int), stream);
    hipMemsetAsync(cursor, 0, NN * sizeof(int), stream);
    hipMemsetAsync(gacc, 0, 264 * sizeof(float), stream);

    k_pre<<<1, 64, 0, stream>>>(We1, ae1, We2, ae2, cbuf);
    k_node1<<<NN, 256, 0, stream>>>(x, W1, as1, ad1, a_src1, a_dst1);
    k_hist<<<(NE + 255) / 256, 256, 0, stream>>>(dst, hist);
    k_scan<<<1, 1024, 0, stream>>>(hist, offs);
    k_scatter<<<(NE + 255) / 256, 256, 0, stream>>>(src, dst, ea, offs, cursor, es_src, es_ea);
    k_conv1<<<512, 512, 0, stream>>>(x, W1, b1, a_src1, a_dst1, cbuf, W2, as2, ad2,
                                     offs, es_src, es_ea, xh2, a_src2, a_dst2);
    k_conv2<<<2048, 256, 0, stream>>>(x, xh2, a_src2, a_dst2, cbuf, b2,
                                      offs, es_src, es_ea, asg, gacc);
    k_head<<<1, 64, 0, stream>>>(gacc, A1, ba1, A2, ba2, C1, bc1, C2, bc2, (float*)d_out);
}

// Round 2
// 380.336 us; speedup vs baseline: 2.1172x; 2.1172x over previous
//
#include <hip/hip_runtime.h>

#define NN 100000
#define NE 800000

typedef short bf16x8 __attribute__((ext_vector_type(8)));
typedef float f32x4 __attribute__((ext_vector_type(4)));

__device__ __forceinline__ float wave_reduce_sum(float v) {
    #pragma unroll
    for (int o = 32; o > 0; o >>= 1) v += __shfl_down(v, o, 64);
    return v; // valid in lane 0
}

__device__ __forceinline__ unsigned short f2bf(float f) {
    unsigned u = __float_as_uint(f);
    unsigned r = (u + 0x7FFFu + ((u >> 16) & 1u)) >> 16;
    return (unsigned short)r;
}
__device__ __forceinline__ float bf2f(unsigned short b) {
    return __uint_as_float(((unsigned)b) << 16);
}

// cb layout (floats): [0..27] vs1(k*4+h)  [28..55] vd1  [56..59] c1[h]  [60] c2
//                     [64..319] was2 = W2@as2   [320..575] wad2 = W2@ad2
// Block 0: constants. Blocks 1..64: W2 -> bf16 B-fragment-order swizzle.
__global__ void k_pre(const float* __restrict__ W1, const float* __restrict__ as1,
                      const float* __restrict__ ad1,
                      const float* __restrict__ We1, const float* __restrict__ ae1,
                      const float* __restrict__ We2, const float* __restrict__ ae2,
                      const float* __restrict__ W2, const float* __restrict__ as2,
                      const float* __restrict__ ad2,
                      float* __restrict__ cb, unsigned short* __restrict__ W2fr) {
    int t = threadIdx.x;
    if (blockIdx.x == 0) {
        if (t < 28) {
            int k = t >> 2, h = t & 3;
            float s = 0.f, d = 0.f;
            for (int c = 0; c < 64; ++c) {
                float w = W1[k * 256 + h * 64 + c];
                s += w * as1[h * 64 + c];
                d += w * ad1[h * 64 + c];
            }
            cb[t] = s; cb[28 + t] = d;
        } else if (t < 32) {
            int h = t - 28;
            float s = 0.f;
            for (int c = 0; c < 64; ++c) s += We1[h * 64 + c] * ae1[h * 64 + c];
            cb[56 + h] = s;
        } else if (t == 32) {
            float s = 0.f;
            for (int c = 0; c < 64; ++c) s += We2[c] * ae2[c];
            cb[60] = s;
        }
        float s = 0.f, d = 0.f;
        for (int j = 0; j < 64; ++j) {
            float w = W2[t * 64 + j];
            s += w * as2[j];
            d += w * ad2[j];
        }
        cb[64 + t] = s;
        cb[320 + t] = d;
    } else {
        int o = (blockIdx.x - 1) * 256 + t;        // 0..16383
        int i = o & 7, l = (o >> 3) & 63, ct = (o >> 9) & 3, ks = o >> 11;
        int k = ks * 32 + ((l >> 4) * 8) + i;
        int col = ct * 16 + (l & 15);
        W2fr[o] = f2bf(W2[k * 64 + col]);
    }
}

// per-node conv1 attention coefficients via folded 7x4 tables
__global__ void k_node1(const float* __restrict__ x, const float* __restrict__ cb,
                        float* __restrict__ a_src1, float* __restrict__ a_dst1) {
    int n = blockIdx.x * 256 + threadIdx.x;
    if (n >= NN) return;
    float xv[7];
    #pragma unroll
    for (int k = 0; k < 7; ++k) xv[k] = x[n * 7 + k];
    float s[4] = {0.f, 0.f, 0.f, 0.f}, d[4] = {0.f, 0.f, 0.f, 0.f};
    #pragma unroll
    for (int k = 0; k < 7; ++k)
        #pragma unroll
        for (int h = 0; h < 4; ++h) {
            s[h] += xv[k] * cb[k * 4 + h];
            d[h] += xv[k] * cb[28 + k * 4 + h];
        }
    *(float4*)(a_src1 + n * 4) = make_float4(s[0], s[1], s[2], s[3]);
    *(float4*)(a_dst1 + n * 4) = make_float4(d[0], d[1], d[2], d[3]);
}

__global__ void k_hist(const int* __restrict__ dst, int* __restrict__ hist) {
    int e = blockIdx.x * 256 + threadIdx.x;
    if (e < NE) atomicAdd(&hist[dst[e]], 1);
}

// single-block exclusive scan, 4 elems/thread
__global__ void k_scan(const int* __restrict__ hist, int* __restrict__ offs) {
    __shared__ int wsum[16];
    __shared__ int carry_s;
    int t = threadIdx.x, lane = t & 63, wid = t >> 6;
    if (t == 0) carry_s = 0;
    __syncthreads();
    for (int base = 0; base < NN; base += 4096) {
        int i0 = base + t * 4;
        int v0 = 0, v1 = 0, v2 = 0, v3 = 0;
        if (i0 + 3 < NN) {
            int4 q = *(const int4*)(hist + i0);
            v0 = q.x; v1 = q.y; v2 = q.z; v3 = q.w;
        } else {
            if (i0 < NN) v0 = hist[i0];
            if (i0 + 1 < NN) v1 = hist[i0 + 1];
            if (i0 + 2 < NN) v2 = hist[i0 + 2];
            if (i0 + 3 < NN) v3 = hist[i0 + 3];
        }
        int s0 = v0, s1 = s0 + v1, s2 = s1 + v2, s3 = s2 + v3;
        int w = s3;
        #pragma unroll
        for (int d = 1; d < 64; d <<= 1) { int u = __shfl_up(w, d, 64); if (lane >= d) w += u; }
        if (lane == 63) wsum[wid] = w;
        __syncthreads();
        if (wid == 0) {
            int ws_ = (lane < 16) ? wsum[lane] : 0;
            #pragma unroll
            for (int d = 1; d < 16; d <<= 1) { int u = __shfl_up(ws_, d, 64); if (lane >= d) ws_ += u; }
            if (lane < 16) wsum[lane] = ws_;
        }
        __syncthreads();
        int carry = carry_s;
        int excl = carry + (wid ? wsum[wid - 1] : 0) + (w - s3);
        if (i0 < NN)     offs[i0 + 1] = excl + s0;
        if (i0 + 1 < NN) offs[i0 + 2] = excl + s1;
        if (i0 + 2 < NN) offs[i0 + 3] = excl + s2;
        if (i0 + 3 < NN) offs[i0 + 4] = excl + s3;
        __syncthreads();
        if (t == 1023) carry_s = carry + wsum[15];
        __syncthreads();
    }
    if (t == 0) offs[0] = 0;
}

// scatter into dst-sorted order + fused conv1 edge-weight computation
__global__ void k_scatter(const int* __restrict__ src, const int* __restrict__ dst,
                          const float* __restrict__ ea, const int* __restrict__ offs,
                          const float* __restrict__ a_src1, const float* __restrict__ a_dst1,
                          const float* __restrict__ cb,
                          int* __restrict__ cursor, int* __restrict__ es_src,
                          int* __restrict__ es_dst, float* __restrict__ es_ea,
                          float* __restrict__ es_w) {
    int e = blockIdx.x * 256 + threadIdx.x;
    if (e >= NE) return;
    int s = src[e], d = dst[e];
    int pos = offs[d] + atomicAdd(&cursor[d], 1);
    float eav = ea[e];
    float4 as_ = *(const float4*)(a_src1 + s * 4);
    float4 ad_ = *(const float4*)(a_dst1 + d * 4);
    float lg0 = as_.x + ad_.x + eav * cb[56];
    float lg1 = as_.y + ad_.y + eav * cb[57];
    float lg2 = as_.z + ad_.z + eav * cb[58];
    float lg3 = as_.w + ad_.w + eav * cb[59];
    lg0 = lg0 >= 0.f ? lg0 : 0.2f * lg0;
    lg1 = lg1 >= 0.f ? lg1 : 0.2f * lg1;
    lg2 = lg2 >= 0.f ? lg2 : 0.2f * lg2;
    lg3 = lg3 >= 0.f ? lg3 : 0.2f * lg3;
    es_src[pos] = s;
    es_dst[pos] = d;
    es_ea[pos] = eav;
    *(float4*)(es_w + pos * 4) = make_float4(__expf(lg0), __expf(lg1), __expf(lg2), __expf(lg3));
}

// fused: conv1 reduce (m[4][8] per node) -> h[256] -> a_src2/a_dst2 -> MFMA h@W2 -> xh2 bf16
__global__ __launch_bounds__(256) void k_conv1red(
    const float* __restrict__ x, const float* __restrict__ W1, const float* __restrict__ b1,
    const float* __restrict__ cb, const int* __restrict__ offs,
    const int* __restrict__ es_src, const float* __restrict__ es_w,
    const unsigned short* __restrict__ W2fr,
    unsigned short* __restrict__ xh2b, float* __restrict__ a_src2, float* __restrict__ a_dst2) {
    __shared__ __attribute__((aligned(16))) unsigned short hs[16][264];
    __shared__ float ms[4][32];
    int t = threadIdx.x, lane = t & 63, wid = t >> 6;
    float w1r[7][4], b1r[4], was2r[4], wad2r[4];
    #pragma unroll
    for (int k = 0; k < 7; ++k)
        #pragma unroll
        for (int h = 0; h < 4; ++h) w1r[k][h] = W1[k * 256 + h * 64 + lane];
    #pragma unroll
    for (int h = 0; h < 4; ++h) {
        b1r[h] = b1[h * 64 + lane];
        was2r[h] = cb[64 + h * 64 + lane];
        wad2r[h] = cb[320 + h * 64 + lane];
    }
    int eslot = lane >> 5, hh = (lane >> 3) & 3, kk = lane & 7;
    int n0 = blockIdx.x * 16;
    for (int nl = 0; nl < 4; ++nl) {
        int n = n0 + wid * 4 + nl;
        int o0 = offs[n], o1 = offs[n + 1];
        float m = 0.f;
        for (int j0 = o0; j0 < o1; j0 += 2) {
            int j = j0 + eslot;
            if (j < o1) {
                int s = es_src[j];
                float wv = es_w[j * 4 + hh];
                float xv = (kk < 7) ? x[s * 7 + kk] : 1.f;
                m += wv * xv;
            }
        }
        m += __shfl_xor(m, 32, 64);
        if (lane < 32) ms[wid][lane] = m;
        bool has = o1 > o0;
        float ps = 0.f, pd = 0.f;
        #pragma unroll
        for (int h = 0; h < 4; ++h) {
            float z = ms[wid][h * 8 + 7];
            float a = 0.f;
            #pragma unroll
            for (int k = 0; k < 7; ++k) a += ms[wid][h * 8 + k] * w1r[k][h];
            float mm = (has ? a / z : 0.f) + b1r[h];
            float hv = mm > 0.f ? mm : (__expf(mm) - 1.f);
            ps += hv * was2r[h];
            pd += hv * wad2r[h];
            hs[wid * 4 + nl][h * 64 + lane] = f2bf(hv);
        }
        ps = wave_reduce_sum(ps);
        pd = wave_reduce_sum(pd);
        if (lane == 0) { a_src2[n] = ps; a_dst2[n] = pd; }
    }
    __syncthreads();
    // MFMA: xh2[16 nodes][64 ch]; wave wid owns column tile wid*16..+16
    f32x4 acc = {0.f, 0.f, 0.f, 0.f};
    int row = lane & 15, kg = lane >> 4;
    #pragma unroll
    for (int ks = 0; ks < 8; ++ks) {
        bf16x8 av = *(const bf16x8*)&hs[row][ks * 32 + kg * 8];
        bf16x8 bv = *(const bf16x8*)(W2fr + (((ks * 4 + wid) * 64) + lane) * 8);
        acc = __builtin_amdgcn_mfma_f32_16x16x32_bf16(av, bv, acc, 0, 0, 0);
    }
    #pragma unroll
    for (int i = 0; i < 4; ++i) {
        int r = kg * 4 + i;
        xh2b[(n0 + r) * 64 + wid * 16 + row] = f2bf(acc[i]);
    }
}

// conv2 edge weights (edge-parallel, coalesced)
__global__ void k_edge2(const int* __restrict__ es_src, const int* __restrict__ es_dst,
                        const float* __restrict__ es_ea,
                        const float* __restrict__ a_src2, const float* __restrict__ a_dst2,
                        const float* __restrict__ cb, float* __restrict__ es_w2) {
    int e = blockIdx.x * 256 + threadIdx.x;
    if (e >= NE) return;
    float lg = a_src2[es_src[e]] + a_dst2[es_dst[e]] + es_ea[e] * cb[60];
    lg = lg >= 0.f ? lg : 0.2f * lg;
    es_w2[e] = __expf(lg);
}

// conv2 aggregate + cluster pooling partials
__global__ __launch_bounds__(256) void k_conv2(
    const float* __restrict__ x, const unsigned short* __restrict__ xh2b,
    const float* __restrict__ es_w2, const float* __restrict__ b2,
    const int* __restrict__ offs, const int* __restrict__ es_src,
    const int* __restrict__ assign, float* __restrict__ gacc) {
    __shared__ float csum[264];
    int t = threadIdx.x, lane = t & 63, wid = t >> 6;
    for (int i = t; i < 264; i += 256) csum[i] = 0.f;
    __syncthreads();
    float b2l = b2[lane];
    for (int n = blockIdx.x * 4 + wid; n < NN; n += gridDim.x * 4) {
        int o0 = offs[n], o1 = offs[n + 1];
        float z = 0.f, acc = 0.f;
        for (int j = o0; j < o1; ++j) {
            float w = es_w2[j];
            int s = es_src[j];
            acc += w * bf2f(xh2b[s * 64 + lane]);
            z += w;
        }
        float h2 = ((o1 > o0) ? acc / z : 0.f) + b2l;
        int c = assign[n];
        atomicAdd(&csum[c * 64 + lane], h2);
        if (lane == 0) {
            atomicAdd(&csum[256 + c], 1.f);
            atomicAdd(&csum[260 + c], x[n * 7 + 6]);
        }
    }
    __syncthreads();
    for (int i = t; i < 264; i += 256) atomicAdd(&gacc[i], csum[i]);
}

// final head: cluster means, actor MLP + softmax, critic MLP
__global__ void k_head(const float* __restrict__ gacc,
                       const float* __restrict__ A1, const float* __restrict__ ba1,
                       const float* __restrict__ A2, const float* __restrict__ ba2,
                       const float* __restrict__ C1, const float* __restrict__ bc1,
                       const float* __restrict__ C2, const float* __restrict__ bc2,
                       float* __restrict__ out) {
    __shared__ float zc[4][64];
    __shared__ float cfs[4];
    __shared__ float logits[4];
    int j = threadIdx.x; // 64
    #pragma unroll
    for (int c = 0; c < 4; ++c) {
        float cnt = gacc[256 + c];
        float den = fmaxf(cnt, 1.f);
        zc[c][j] = (cnt > 0.f) ? gacc[c * 64 + j] / den : 0.f;
        if (j == 0) cfs[c] = (cnt > 0.f) ? gacc[260 + c] / den : 0.f;
    }
    __syncthreads();
    #pragma unroll
    for (int c = 0; c < 4; ++c) {
        float tv = ba1[j];
        for (int k = 0; k < 64; ++k) tv += zc[c][k] * A1[k * 64 + j];
        tv += cfs[c] * A1[64 * 64 + j];
        tv = fmaxf(tv, 0.f);
        float s = wave_reduce_sum(tv * A2[j]);
        if (j == 0) logits[c] = s + ba2[0];
    }
    float vj = bc1[j];
    for (int k = 0; k < 256; ++k) vj += zc[k >> 6][k & 63] * C1[k * 64 + j];
    vj = fmaxf(vj, 0.f);
    float v = wave_reduce_sum(vj * C2[j]);
    __syncthreads();
    if (j == 0) {
        float m = fmaxf(fmaxf(logits[0], logits[1]), fmaxf(logits[2], logits[3]));
        float e0 = __expf(logits[0] - m), e1 = __expf(logits[1] - m);
        float e2 = __expf(logits[2] - m), e3 = __expf(logits[3] - m);
        float sum = e0 + e1 + e2 + e3;
        out[0] = e0 / sum; out[1] = e1 / sum; out[2] = e2 / sum; out[3] = e3 / sum;
        out[4] = v + bc2[0];
    }
    #pragma unroll
    for (int c = 0; c < 4; ++c) out[5 + c * 64 + j] = zc[c][j];
}

extern "C" void kernel_launch(void* const* d_in, const int* in_sizes, int n_in,
                              void* d_out, int out_size, void* d_ws, size_t ws_size,
                              hipStream_t stream) {
    const float* x    = (const float*)d_in[0];
    const int*   ei   = (const int*)d_in[1];
    const float* ea   = (const float*)d_in[2];
    const int*   asg  = (const int*)d_in[3];
    const float* W1   = (const float*)d_in[4];
    const float* as1  = (const float*)d_in[5];
    const float* ad1  = (const float*)d_in[6];
    const float* We1  = (const float*)d_in[7];
    const float* ae1  = (const float*)d_in[8];
    const float* b1   = (const float*)d_in[9];
    const float* W2   = (const float*)d_in[10];
    const float* as2  = (const float*)d_in[11];
    const float* ad2  = (const float*)d_in[12];
    const float* We2  = (const float*)d_in[13];
    const float* ae2  = (const float*)d_in[14];
    const float* b2   = (const float*)d_in[15];
    const float* A1   = (const float*)d_in[16];
    const float* ba1  = (const float*)d_in[17];
    const float* A2   = (const float*)d_in[18];
    const float* ba2  = (const float*)d_in[19];
    const float* C1   = (const float*)d_in[20];
    const float* bc1  = (const float*)d_in[21];
    const float* C2   = (const float*)d_in[22];
    const float* bc2  = (const float*)d_in[23];
    const int* src = ei;
    const int* dst = ei + NE;

    char* w = (char*)d_ws;
    size_t off = 0;
    auto alloc = [&](size_t bytes) -> void* {
        void* p = w + off;
        off += (bytes + 255) & ~(size_t)255;
        return p;
    };
    float* a_src1 = (float*)alloc(NN * 4 * sizeof(float));
    float* a_dst1 = (float*)alloc(NN * 4 * sizeof(float));
    float* a_src2 = (float*)alloc(NN * sizeof(float));
    float* a_dst2 = (float*)alloc(NN * sizeof(float));
    int*   hist   = (int*)alloc(NN * sizeof(int));
    int*   offs   = (int*)alloc((NN + 1) * sizeof(int));
    int*   cursor = (int*)alloc(NN * sizeof(int));
    int*   es_src = (int*)alloc(NE * sizeof(int));
    int*   es_dst = (int*)alloc(NE * sizeof(int));
    float* es_ea  = (float*)alloc(NE * sizeof(float));
    float* es_w   = (float*)alloc(NE * 4 * sizeof(float));
    float* es_w2  = (float*)alloc(NE * sizeof(float));
    unsigned short* xh2b = (unsigned short*)alloc(NN * 64 * sizeof(unsigned short));
    unsigned short* W2fr = (unsigned short*)alloc(16384 * sizeof(unsigned short));
    float* cb     = (float*)alloc(576 * sizeof(float));
    float* gacc   = (float*)alloc(264 * sizeof(float));
    (void)ws_size; (void)n_in; (void)in_sizes; (void)out_size;

    hipMemsetAsync(hist, 0, NN * sizeof(int), stream);
    hipMemsetAsync(cursor, 0, NN * sizeof(int), stream);
    hipMemsetAsync(gacc, 0, 264 * sizeof(float), stream);

    k_pre<<<65, 256, 0, stream>>>(W1, as1, ad1, We1, ae1, We2, ae2, W2, as2, ad2, cb, W2fr);
    k_node1<<<(NN + 255) / 256, 256, 0, stream>>>(x, cb, a_src1, a_dst1);
    k_hist<<<(NE + 255) / 256, 256, 0, stream>>>(dst, hist);
    k_scan<<<1, 1024, 0, stream>>>(hist, offs);
    k_scatter<<<(NE + 255) / 256, 256, 0, stream>>>(src, dst, ea, offs, a_src1, a_dst1, cb,
                                                    cursor, es_src, es_dst, es_ea, es_w);
    k_conv1red<<<NN / 16, 256, 0, stream>>>(x, W1, b1, cb, offs, es_src, es_w, W2fr,
                                            xh2b, a_src2, a_dst2);
    k_edge2<<<(NE + 255) / 256, 256, 0, stream>>>(es_src, es_dst, es_ea, a_src2, a_dst2, cb, es_w2);
    k_conv2<<<2048, 256, 0, stream>>>(x, xh2b, es_w2, b2, offs, es_src, asg, gacc);
    k_head<<<1, 64, 0, stream>>>(gacc, A1, ba1, A2, ba2, C1, bc1, C2, bc2, (float*)d_out);
}

// Round 3
// 287.744 us; speedup vs baseline: 2.7985x; 1.3218x over previous
//
#include <hip/hip_runtime.h>

#define NN 100000
#define NE 800000

typedef short bf16x8 __attribute__((ext_vector_type(8)));
typedef float f32x4 __attribute__((ext_vector_type(4)));

__device__ __forceinline__ float wave_reduce_sum(float v) {
    #pragma unroll
    for (int o = 32; o > 0; o >>= 1) v += __shfl_down(v, o, 64);
    return v; // valid in lane 0
}

__device__ __forceinline__ unsigned short f2bf(float f) {
    unsigned u = __float_as_uint(f);
    unsigned r = (u + 0x7FFFu + ((u >> 16) & 1u)) >> 16;
    return (unsigned short)r;
}
__device__ __forceinline__ float bf2f(unsigned short b) {
    return __uint_as_float(((unsigned)b) << 16);
}

// cb layout (floats): [0..27] vs1(k*4+h)  [28..55] vd1  [56..59] c1[h]  [60] c2
//                     [64..319] was2 = W2@as2   [320..575] wad2 = W2@ad2
__global__ void k_pre(const float* __restrict__ W1, const float* __restrict__ as1,
                      const float* __restrict__ ad1,
                      const float* __restrict__ We1, const float* __restrict__ ae1,
                      const float* __restrict__ We2, const float* __restrict__ ae2,
                      const float* __restrict__ W2, const float* __restrict__ as2,
                      const float* __restrict__ ad2,
                      float* __restrict__ cb, unsigned short* __restrict__ W2fr) {
    int t = threadIdx.x;
    if (blockIdx.x == 0) {
        if (t < 28) {
            int k = t >> 2, h = t & 3;
            float s = 0.f, d = 0.f;
            for (int c = 0; c < 64; ++c) {
                float w = W1[k * 256 + h * 64 + c];
                s += w * as1[h * 64 + c];
                d += w * ad1[h * 64 + c];
            }
            cb[t] = s; cb[28 + t] = d;
        } else if (t < 32) {
            int h = t - 28;
            float s = 0.f;
            for (int c = 0; c < 64; ++c) s += We1[h * 64 + c] * ae1[h * 64 + c];
            cb[56 + h] = s;
        } else if (t == 32) {
            float s = 0.f;
            for (int c = 0; c < 64; ++c) s += We2[c] * ae2[c];
            cb[60] = s;
        }
        float s = 0.f, d = 0.f;
        for (int j = 0; j < 64; ++j) {
            float w = W2[t * 64 + j];
            s += w * as2[j];
            d += w * ad2[j];
        }
        cb[64 + t] = s;
        cb[320 + t] = d;
    } else {
        int o = (blockIdx.x - 1) * 256 + t;        // 0..16383
        int i = o & 7, l = (o >> 3) & 63, ct = (o >> 9) & 3, ks = o >> 11;
        int k = ks * 32 + ((l >> 4) * 8) + i;
        int col = ct * 16 + (l & 15);
        W2fr[o] = f2bf(W2[k * 64 + col]);
    }
}

// per-node conv1 attention coefficients via folded 7x4 tables
__global__ void k_node1(const float* __restrict__ x, const float* __restrict__ cb,
                        float* __restrict__ a_src1, float* __restrict__ a_dst1) {
    int n = blockIdx.x * 256 + threadIdx.x;
    if (n >= NN) return;
    float xv[7];
    #pragma unroll
    for (int k = 0; k < 7; ++k) xv[k] = x[n * 7 + k];
    float s[4] = {0.f, 0.f, 0.f, 0.f}, d[4] = {0.f, 0.f, 0.f, 0.f};
    #pragma unroll
    for (int k = 0; k < 7; ++k)
        #pragma unroll
        for (int h = 0; h < 4; ++h) {
            s[h] += xv[k] * cb[k * 4 + h];
            d[h] += xv[k] * cb[28 + k * 4 + h];
        }
    *(float4*)(a_src1 + n * 4) = make_float4(s[0], s[1], s[2], s[3]);
    *(float4*)(a_dst1 + n * 4) = make_float4(d[0], d[1], d[2], d[3]);
}

__global__ void k_hist(const int* __restrict__ dst, int* __restrict__ hist) {
    int e0 = (blockIdx.x * 256 + threadIdx.x) * 4;
    if (e0 >= NE) return;
    int4 d = *(const int4*)(dst + e0);
    atomicAdd(&hist[d.x], 1);
    atomicAdd(&hist[d.y], 1);
    atomicAdd(&hist[d.z], 1);
    atomicAdd(&hist[d.w], 1);
}

// --- 3-phase parallel exclusive scan over hist[NN] -> offs[NN+1], cursor[NN] ---
__global__ __launch_bounds__(1024) void k_scanA(const int* __restrict__ hist,
                                                int* __restrict__ bsum) {
    __shared__ int ws[16];
    int i = blockIdx.x * 1024 + threadIdx.x;
    int lane = threadIdx.x & 63, wid = threadIdx.x >> 6;
    int v = (i < NN) ? hist[i] : 0;
    #pragma unroll
    for (int o = 32; o; o >>= 1) v += __shfl_down(v, o, 64);
    if (lane == 0) ws[wid] = v;
    __syncthreads();
    if (wid == 0) {
        int u = (lane < 16) ? ws[lane] : 0;
        #pragma unroll
        for (int o = 8; o; o >>= 1) u += __shfl_down(u, o, 64);
        if (lane == 0) bsum[blockIdx.x] = u;
    }
}

__global__ void k_scanB(const int* __restrict__ bsum, int* __restrict__ bexcl) {
    __shared__ int w0tot;
    int t = threadIdx.x, lane = t & 63, wid = t >> 6;
    int v = (t < 98) ? bsum[t] : 0;
    int s = v;
    #pragma unroll
    for (int d = 1; d < 64; d <<= 1) { int u = __shfl_up(s, d, 64); if (lane >= d) s += u; }
    if (t == 63) w0tot = s;
    __syncthreads();
    if (wid == 1) s += w0tot;
    if (t < 98) bexcl[t] = s - v;
}

__global__ __launch_bounds__(1024) void k_scanC(const int* __restrict__ hist,
                                                const int* __restrict__ bexcl,
                                                int* __restrict__ offs,
                                                int* __restrict__ cursor) {
    __shared__ int ws[16];
    int b = blockIdx.x;
    int i = b * 1024 + threadIdx.x;
    int lane = threadIdx.x & 63, wid = threadIdx.x >> 6;
    int v = (i < NN) ? hist[i] : 0;
    int s = v;
    #pragma unroll
    for (int d = 1; d < 64; d <<= 1) { int u = __shfl_up(s, d, 64); if (lane >= d) s += u; }
    if (lane == 63) ws[wid] = s;
    __syncthreads();
    if (wid == 0) {
        int u2 = (lane < 16) ? ws[lane] : 0;
        #pragma unroll
        for (int d = 1; d < 16; d <<= 1) { int uu = __shfl_up(u2, d, 64); if (lane >= d) u2 += uu; }
        if (lane < 16) ws[lane] = u2;
    }
    __syncthreads();
    int incl = s + (wid ? ws[wid - 1] : 0) + bexcl[b];
    if (i < NN) { offs[i + 1] = incl; cursor[i] = incl - v; }
    if (i == 0) offs[0] = 0;
}

// scatter into dst-sorted order + fused conv1 edge-weight computation
__global__ void k_scatter(const int* __restrict__ src, const int* __restrict__ dst,
                          const float* __restrict__ ea,
                          const float* __restrict__ a_src1, const float* __restrict__ a_dst1,
                          const float* __restrict__ cb,
                          int* __restrict__ cursor, int* __restrict__ es_src,
                          int* __restrict__ es_pos, float* __restrict__ es_w) {
    int e = blockIdx.x * 256 + threadIdx.x;
    if (e >= NE) return;
    int s = src[e], d = dst[e];
    int pos = atomicAdd(&cursor[d], 1);
    float eav = ea[e];
    float4 as_ = *(const float4*)(a_src1 + s * 4);
    float4 ad_ = *(const float4*)(a_dst1 + d * 4);
    float lg0 = as_.x + ad_.x + eav * cb[56];
    float lg1 = as_.y + ad_.y + eav * cb[57];
    float lg2 = as_.z + ad_.z + eav * cb[58];
    float lg3 = as_.w + ad_.w + eav * cb[59];
    lg0 = lg0 >= 0.f ? lg0 : 0.2f * lg0;
    lg1 = lg1 >= 0.f ? lg1 : 0.2f * lg1;
    lg2 = lg2 >= 0.f ? lg2 : 0.2f * lg2;
    lg3 = lg3 >= 0.f ? lg3 : 0.2f * lg3;
    es_src[pos] = s;
    es_pos[e] = pos;
    *(float4*)(es_w + pos * 4) = make_float4(__expf(lg0), __expf(lg1), __expf(lg2), __expf(lg3));
}

// fused: conv1 reduce (m[4][8] per node, 8-edge batched) -> h -> a_src2/a_dst2 -> MFMA -> xh2 bf16
__global__ __launch_bounds__(256) void k_conv1red(
    const float* __restrict__ x, const float* __restrict__ W1, const float* __restrict__ b1,
    const float* __restrict__ cb, const int* __restrict__ offs,
    const int* __restrict__ es_src, const float* __restrict__ es_w,
    const unsigned short* __restrict__ W2fr,
    unsigned short* __restrict__ xh2b, float* __restrict__ a_src2, float* __restrict__ a_dst2) {
    __shared__ __attribute__((aligned(16))) unsigned short hs[16][264];
    __shared__ float ms[4][32];
    int t = threadIdx.x, lane = t & 63, wid = t >> 6;
    float w1r[7][4], b1r[4], was2r[4], wad2r[4];
    #pragma unroll
    for (int k = 0; k < 7; ++k)
        #pragma unroll
        for (int h = 0; h < 4; ++h) w1r[k][h] = W1[k * 256 + h * 64 + lane];
    #pragma unroll
    for (int h = 0; h < 4; ++h) {
        b1r[h] = b1[h * 64 + lane];
        was2r[h] = cb[64 + h * 64 + lane];
        wad2r[h] = cb[320 + h * 64 + lane];
    }
    int eslot = lane >> 5, hh = (lane >> 3) & 3, kk = lane & 7;
    int n0 = blockIdx.x * 16;
    for (int nl = 0; nl < 4; ++nl) {
        int n = n0 + wid * 4 + nl;
        int o0 = offs[n], o1 = offs[n + 1];
        float m = 0.f;
        for (int j = o0; j < o1; j += 8) {
            int sl = 0; float wl = 0.f;
            if (lane < 8 && j + lane < o1) sl = es_src[j + lane];
            if (lane < 32 && j + (lane >> 2) < o1) wl = es_w[j * 4 + lane];
            #pragma unroll
            for (int p = 0; p < 4; ++p) {
                int s = __shfl(sl, p * 2 + eslot, 64);
                float w = __shfl(wl, (p * 2 + eslot) * 4 + hh, 64);
                float xv = (kk < 7) ? x[s * 7 + kk] : 1.f;
                m = fmaf(w, xv, m);
            }
        }
        m += __shfl_xor(m, 32, 64);
        if (lane < 32) ms[wid][lane] = m;
        bool has = o1 > o0;
        float ps = 0.f, pd = 0.f;
        #pragma unroll
        for (int h = 0; h < 4; ++h) {
            float z = ms[wid][h * 8 + 7];
            float a = 0.f;
            #pragma unroll
            for (int k = 0; k < 7; ++k) a += ms[wid][h * 8 + k] * w1r[k][h];
            float mm = (has ? a / z : 0.f) + b1r[h];
            float hv = mm > 0.f ? mm : (__expf(mm) - 1.f);
            ps += hv * was2r[h];
            pd += hv * wad2r[h];
            hs[wid * 4 + nl][h * 64 + lane] = f2bf(hv);
        }
        ps = wave_reduce_sum(ps);
        pd = wave_reduce_sum(pd);
        if (lane == 0) { a_src2[n] = ps; a_dst2[n] = pd; }
    }
    __syncthreads();
    // MFMA: xh2[16 nodes][64 ch]; wave wid owns column tile wid*16..+16
    f32x4 acc = {0.f, 0.f, 0.f, 0.f};
    int row = lane & 15, kg = lane >> 4;
    #pragma unroll
    for (int ks = 0; ks < 8; ++ks) {
        bf16x8 av = *(const bf16x8*)&hs[row][ks * 32 + kg * 8];
        bf16x8 bv = *(const bf16x8*)(W2fr + (((ks * 4 + wid) * 64) + lane) * 8);
        acc = __builtin_amdgcn_mfma_f32_16x16x32_bf16(av, bv, acc, 0, 0, 0);
    }
    #pragma unroll
    for (int i = 0; i < 4; ++i) {
        int r = kg * 4 + i;
        xh2b[(n0 + r) * 64 + wid * 16 + row] = f2bf(acc[i]);
    }
}

// conv2 edge weights, original edge order (coalesced reads), scattered 4B write
__global__ void k_edge2(const int* __restrict__ src, const int* __restrict__ dst,
                        const float* __restrict__ ea, const int* __restrict__ es_pos,
                        const float* __restrict__ a_src2, const float* __restrict__ a_dst2,
                        const float* __restrict__ cb, float* __restrict__ es_w2) {
    int e = blockIdx.x * 256 + threadIdx.x;
    if (e >= NE) return;
    float lg = a_src2[src[e]] + a_dst2[dst[e]] + ea[e] * cb[60];
    lg = lg >= 0.f ? lg : 0.2f * lg;
    es_w2[es_pos[e]] = __expf(lg);
}

// conv2 aggregate (8-edge batched gathers) + cluster pooling partials
__global__ __launch_bounds__(256) void k_conv2(
    const float* __restrict__ x, const unsigned short* __restrict__ xh2b,
    const float* __restrict__ es_w2, const float* __restrict__ b2,
    const int* __restrict__ offs, const int* __restrict__ es_src,
    const int* __restrict__ assign, float* __restrict__ gacc) {
    __shared__ float csum[264];
    int t = threadIdx.x, lane = t & 63, wid = t >> 6;
    for (int i = t; i < 264; i += 256) csum[i] = 0.f;
    __syncthreads();
    float b2l = b2[lane];
    for (int n = blockIdx.x * 4 + wid; n < NN; n += gridDim.x * 4) {
        int o0 = offs[n], o1 = offs[n + 1];
        float z = 0.f, acc = 0.f;
        for (int j = o0; j < o1; j += 8) {
            int sl = 0; float wl = 0.f;
            if (lane < 8 && j + lane < o1) {
                sl = es_src[j + lane];
                wl = es_w2[j + lane];
            }
            #pragma unroll
            for (int u = 0; u < 8; ++u) {
                int s = __shfl(sl, u, 64);
                float w = __shfl(wl, u, 64);
                acc = fmaf(w, bf2f(xh2b[s * 64 + lane]), acc);
                z += w;
            }
        }
        float h2 = ((o1 > o0) ? acc / z : 0.f) + b2l;
        int c = assign[n];
        atomicAdd(&csum[c * 64 + lane], h2);
        if (lane == 0) {
            atomicAdd(&csum[256 + c], 1.f);
            atomicAdd(&csum[260 + c], x[n * 7 + 6]);
        }
    }
    __syncthreads();
    for (int i = t; i < 264; i += 256) atomicAdd(&gacc[i], csum[i]);
}

// final head: cluster means, actor MLP + softmax, critic MLP
__global__ void k_head(const float* __restrict__ gacc,
                       const float* __restrict__ A1, const float* __restrict__ ba1,
                       const float* __restrict__ A2, const float* __restrict__ ba2,
                       const float* __restrict__ C1, const float* __restrict__ bc1,
                       const float* __restrict__ C2, const float* __restrict__ bc2,
                       float* __restrict__ out) {
    __shared__ float zc[4][64];
    __shared__ float cfs[4];
    __shared__ float logits[4];
    int j = threadIdx.x; // 64
    #pragma unroll
    for (int c = 0; c < 4; ++c) {
        float cnt = gacc[256 + c];
        float den = fmaxf(cnt, 1.f);
        zc[c][j] = (cnt > 0.f) ? gacc[c * 64 + j] / den : 0.f;
        if (j == 0) cfs[c] = (cnt > 0.f) ? gacc[260 + c] / den : 0.f;
    }
    __syncthreads();
    #pragma unroll
    for (int c = 0; c < 4; ++c) {
        float tv = ba1[j];
        for (int k = 0; k < 64; ++k) tv += zc[c][k] * A1[k * 64 + j];
        tv += cfs[c] * A1[64 * 64 + j];
        tv = fmaxf(tv, 0.f);
        float s = wave_reduce_sum(tv * A2[j]);
        if (j == 0) logits[c] = s + ba2[0];
    }
    float vj = bc1[j];
    for (int k = 0; k < 256; ++k) vj += zc[k >> 6][k & 63] * C1[k * 64 + j];
    vj = fmaxf(vj, 0.f);
    float v = wave_reduce_sum(vj * C2[j]);
    __syncthreads();
    if (j == 0) {
        float m = fmaxf(fmaxf(logits[0], logits[1]), fmaxf(logits[2], logits[3]));
        float e0 = __expf(logits[0] - m), e1 = __expf(logits[1] - m);
        float e2 = __expf(logits[2] - m), e3 = __expf(logits[3] - m);
        float sum = e0 + e1 + e2 + e3;
        out[0] = e0 / sum; out[1] = e1 / sum; out[2] = e2 / sum; out[3] = e3 / sum;
        out[4] = v + bc2[0];
    }
    #pragma unroll
    for (int c = 0; c < 4; ++c) out[5 + c * 64 + j] = zc[c][j];
}

extern "C" void kernel_launch(void* const* d_in, const int* in_sizes, int n_in,
                              void* d_out, int out_size, void* d_ws, size_t ws_size,
                              hipStream_t stream) {
    const float* x    = (const float*)d_in[0];
    const int*   ei   = (const int*)d_in[1];
    const float* ea   = (const float*)d_in[2];
    const int*   asg  = (const int*)d_in[3];
    const float* W1   = (const float*)d_in[4];
    const float* as1  = (const float*)d_in[5];
    const float* ad1  = (const float*)d_in[6];
    const float* We1  = (const float*)d_in[7];
    const float* ae1  = (const float*)d_in[8];
    const float* b1   = (const float*)d_in[9];
    const float* W2   = (const float*)d_in[10];
    const float* as2  = (const float*)d_in[11];
    const float* ad2  = (const float*)d_in[12];
    const float* We2  = (const float*)d_in[13];
    const float* ae2  = (const float*)d_in[14];
    const float* b2   = (const float*)d_in[15];
    const float* A1   = (const float*)d_in[16];
    const float* ba1  = (const float*)d_in[17];
    const float* A2   = (const float*)d_in[18];
    const float* ba2  = (const float*)d_in[19];
    const float* C1   = (const float*)d_in[20];
    const float* bc1  = (const float*)d_in[21];
    const float* C2   = (const float*)d_in[22];
    const float* bc2  = (const float*)d_in[23];
    const int* src = ei;
    const int* dst = ei + NE;

    char* w = (char*)d_ws;
    size_t off = 0;
    auto alloc = [&](size_t bytes) -> void* {
        void* p = w + off;
        off += (bytes + 255) & ~(size_t)255;
        return p;
    };
    float* a_src1 = (float*)alloc(NN * 4 * sizeof(float));
    float* a_dst1 = (float*)alloc(NN * 4 * sizeof(float));
    float* a_src2 = (float*)alloc(NN * sizeof(float));
    float* a_dst2 = (float*)alloc(NN * sizeof(float));
    int*   hist   = (int*)alloc(NN * sizeof(int));
    int*   offs   = (int*)alloc((NN + 1) * sizeof(int));
    int*   cursor = (int*)alloc(NN * sizeof(int));
    int*   bsum   = (int*)alloc(128 * sizeof(int));
    int*   bexcl  = (int*)alloc(128 * sizeof(int));
    int*   es_src = (int*)alloc(NE * sizeof(int));
    int*   es_pos = (int*)alloc(NE * sizeof(int));
    float* es_w   = (float*)alloc(NE * 4 * sizeof(float));
    float* es_w2  = (float*)alloc(NE * sizeof(float));
    unsigned short* xh2b = (unsigned short*)alloc(NN * 64 * sizeof(unsigned short));
    unsigned short* W2fr = (unsigned short*)alloc(16384 * sizeof(unsigned short));
    float* cb     = (float*)alloc(576 * sizeof(float));
    float* gacc   = (float*)alloc(264 * sizeof(float));
    (void)ws_size; (void)n_in; (void)in_sizes; (void)out_size;

    hipMemsetAsync(hist, 0, NN * sizeof(int), stream);
    hipMemsetAsync(gacc, 0, 264 * sizeof(float), stream);

    k_pre<<<65, 256, 0, stream>>>(W1, as1, ad1, We1, ae1, We2, ae2, W2, as2, ad2, cb, W2fr);
    k_node1<<<(NN + 255) / 256, 256, 0, stream>>>(x, cb, a_src1, a_dst1);
    k_hist<<<(NE / 4 + 255) / 256, 256, 0, stream>>>(dst, hist);
    k_scanA<<<98, 1024, 0, stream>>>(hist, bsum);
    k_scanB<<<1, 128, 0, stream>>>(bsum, bexcl);
    k_scanC<<<98, 1024, 0, stream>>>(hist, bexcl, offs, cursor);
    k_scatter<<<(NE + 255) / 256, 256, 0, stream>>>(src, dst, ea, a_src1, a_dst1, cb,
                                                    cursor, es_src, es_pos, es_w);
    k_conv1red<<<NN / 16, 256, 0, stream>>>(x, W1, b1, cb, offs, es_src, es_w, W2fr,
                                            xh2b, a_src2, a_dst2);
    k_edge2<<<(NE + 255) / 256, 256, 0, stream>>>(src, dst, ea, es_pos, a_src2, a_dst2, cb, es_w2);
    k_conv2<<<2048, 256, 0, stream>>>(x, xh2b, es_w2, b2, offs, es_src, asg, gacc);
    k_head<<<1, 64, 0, stream>>>(gacc, A1, ba1, A2, ba2, C1, bc1, C2, bc2, (float*)d_out);
}